// Round 9
// baseline (170.802 us; speedup 1.0000x reference)
//
#include <hip/hip_runtime.h>

// Segment-mean of subtoken embeddings (sorted per-row segment ids) -> token means.
//
// Round-9: STACK the two independently-confirmed mechanisms:
//   (r6) chunk streamer: 16 known-address row loads in flight per lane,
//        zero dependent prologue (addresses from blockIdx alone);
//   (r7) nontemporal loads: homogeneous HBM read stream (bypasses the
//        ~2.1 TB/s mixed L3-hit/HBM-miss return-path wall; confirmed -8us).
// r6 measured ~58us under the mixed regime; r7 measured ~44us with a
// dependent-prologue structure. This kernel is r6's exact (absmax-0-verified)
// structure with NT loads/stores only -- semantics and accumulation order
// unchanged.
//
// Phase 1 (bounds_pairs_kernel): pairs[b*T+t] = {global_lo, global_hi}.
// Phase 2+3 merged (seg_mean_chunk_d768):
//   - Chunk blocks: own 16 consecutive global rows; flush tokens complete
//     within the chunk (wave-uniform run walk on the seg window).
//   - Fixup blocks: one token per wave; exit after one 8B pairs load if the
//     token was chunk-complete; else (straddlers/empties) gather/zero.

typedef float f32x4_v __attribute__((ext_vector_type(4)));

#define CHUNK 16
#define CHUNK_SHIFT 4

__global__ void bounds_pairs_kernel(const int* __restrict__ seg,
                                    const int* __restrict__ num_tokens_p,
                                    int2* __restrict__ pairs,   // [B*T] global-row bounds
                                    int BS_total,               // B*S
                                    int BT) {                   // B*T
  const int T = num_tokens_p[0];
  const int B = BT / T;
  const int S = BS_total / B;
  const int idx = blockIdx.x * blockDim.x + threadIdx.x;
  if (idx >= BS_total) return;
  const int b = idx / S;
  const int s = idx - b * S;
  const int cur = seg[idx];
  const int prev = (s == 0) ? -1 : seg[idx - 1];
  int2* __restrict__ prow = pairs + (size_t)b * T;

  for (int t = prev + 1; t <= cur; ++t) {
    prow[t].x = idx;                 // lo(t): global row index
    if (t > 0) prow[t - 1].y = idx;  // hi(t-1) = lo(t)
  }
  if (s == S - 1) {
    const int end = b * S + S;
    for (int t = cur + 1; t <= T; ++t) {
      if (t < T) prow[t].x = end;
      prow[t - 1].y = end;
    }
  }
}

// D == 768: 192 threads; chunk role: lane owns one float4 column;
// fixup role: 3 waves, lane owns columns {lane, lane+64, lane+128}.
__global__ void __launch_bounds__(192) seg_mean_chunk_d768(
    const float* __restrict__ hs,      // [B, S, 768]
    const int*   __restrict__ seg,     // [B*S]
    const int2*  __restrict__ pairs,   // [B*T]
    const int*   __restrict__ num_tokens_p,
    float*       __restrict__ out,     // [B, T, 768]
    int BS_total,
    int BT,
    int nChunks) {
  const int T = num_tokens_p[0];
  const int B = BT / T;
  const int S = BS_total / B;

  if ((int)blockIdx.x < nChunks) {
    // ---------------- chunk-stream role ----------------
    const int r0 = blockIdx.x * CHUNK;
    const int d4 = threadIdx.x;                       // [0,192)
    const int rows = (BS_total - r0 < CHUNK) ? (BS_total - r0) : CHUNK;

    // Issue all row loads FIRST — addresses depend only on blockIdx.
    const f32x4_v* __restrict__ hsv = (const f32x4_v*)hs;
    f32x4_v rv[CHUNK];
#pragma unroll
    for (int i = 0; i < CHUNK; ++i) {
      if (i < rows)
        rv[i] = __builtin_nontemporal_load(hsv + (size_t)(r0 + i) * 192 + d4);
      else
        rv[i] = (f32x4_v){0.f, 0.f, 0.f, 0.f};
    }

    // Token-gid window sv[0..17]: sv[0]=gid(r0-1), sv[1..16]=gid(r0+i),
    // sv[17]=gid(r0+16). -1 marks out-of-data. Batch-crossing handled
    // incrementally.
    int sv[CHUNK + 2];
    {
      int bb = r0 / S;
      int rib = r0 - bb * S;
      sv[0] = (r0 == 0) ? -1
            : (((rib == 0) ? (bb - 1) : bb) * T + seg[r0 - 1]);
      int bi = bb, ri = rib;
#pragma unroll
      for (int i = 0; i < CHUNK; ++i) {
        if (ri >= S) { ri -= S; ++bi; }
        sv[i + 1] = (i < rows) ? (bi * T + seg[r0 + i]) : -1;
        ++ri;
      }
      if (ri >= S) { ri -= S; ++bi; }
      sv[CHUNK + 1] = (rows == CHUNK && r0 + CHUNK < BS_total)
                        ? (bi * T + seg[r0 + CHUNK]) : -1;
    }

    // Walk rows; flush runs complete within this chunk. Wave-uniform control
    // flow; per-run accumulation strictly sequential (absmax must stay 0).
    f32x4_v acc = {0.f, 0.f, 0.f, 0.f};
    int runStart = 0;
#pragma unroll
    for (int i = 0; i < CHUNK; ++i) {
      acc = acc + rv[i];
      if (sv[i + 2] != sv[i + 1]) {                   // run ends at row i
        if (sv[i + 1] >= 0 && (runStart > 0 || sv[0] != sv[1])) {
          const int cnt = i - runStart + 1;
          const f32x4_v o = acc * (1.0f / (float)cnt);
          __builtin_nontemporal_store(
              o, (f32x4_v*)out + (size_t)sv[i + 1] * 192 + d4);
        }
        acc = (f32x4_v){0.f, 0.f, 0.f, 0.f};
        runStart = i + 1;
      }
    }
  } else {
    // ---------------- fixup role: 3 waves, one token each ----------------
    const int g = ((int)blockIdx.x - nChunks) * 3 + (threadIdx.x >> 6);
    if (g >= BT) return;
    const int2 lh = pairs[g];
    const int cnt = lh.y - lh.x;
    if (cnt > 0 && ((lh.x >> CHUNK_SHIFT) == ((lh.y - 1) >> CHUNK_SHIFT)))
      return;                                         // chunk role handled it

    const int lane = threadIdx.x & 63;
    const f32x4_v* __restrict__ p =
        (const f32x4_v*)hs + (size_t)lh.x * 192 + lane;
    f32x4_v a0 = {0.f, 0.f, 0.f, 0.f};
    f32x4_v a1 = a0, a2 = a0;
    for (int r = 0; r < cnt; ++r) {
      const f32x4_v v0 = __builtin_nontemporal_load(p);
      const f32x4_v v1 = __builtin_nontemporal_load(p + 64);
      const f32x4_v v2 = __builtin_nontemporal_load(p + 128);
      a0 = a0 + v0;                    // sequential order per token
      a1 = a1 + v1;
      a2 = a2 + v2;
      p += 192;
    }
    const float inv = (cnt > 0) ? (1.0f / (float)cnt) : 0.0f;
    f32x4_v* __restrict__ q = (f32x4_v*)out + (size_t)g * 192 + lane;
    __builtin_nontemporal_store(a0 * inv, q);
    __builtin_nontemporal_store(a1 * inv, q + 64);
    __builtin_nontemporal_store(a2 * inv, q + 128);
  }
}

// Generic-D fallback (D % 4 == 0): one wave per token, column-strided.
__global__ void __launch_bounds__(256) seg_mean_generic(
    const float* __restrict__ hs,
    const int2*  __restrict__ pairs,
    float*       __restrict__ out,
    int BT,
    int dv4) {
  const int wave = threadIdx.x >> 6;
  const int lane = threadIdx.x & 63;
  const int gstride = gridDim.x * 4;

  for (int g = blockIdx.x * 4 + wave; g < BT; g += gstride) {
    const int2 lh = pairs[g];
    const int cnt = lh.y - lh.x;
    const float inv = (cnt > 0) ? (1.0f / (float)cnt) : 0.0f;

    for (int c = lane; c < dv4; c += 64) {
      const float4* __restrict__ p = (const float4*)hs + (size_t)lh.x * dv4 + c;
      float4 acc = make_float4(0.f, 0.f, 0.f, 0.f);
      for (int r = 0; r < cnt; ++r) {
        float4 v = *p;
        acc.x += v.x; acc.y += v.y; acc.z += v.z; acc.w += v.w;
        p += dv4;
      }
      ((float4*)(out + (size_t)g * (dv4 * 4)))[c] =
          make_float4(acc.x * inv, acc.y * inv, acc.z * inv, acc.w * inv);
    }
  }
}

// Workspace-too-small fallback (correctness only).
__global__ void __launch_bounds__(192) seg_mean_search_kernel(
    const float* __restrict__ hs,
    const int* __restrict__ seg,
    const int* __restrict__ num_tokens_p,
    float* __restrict__ out,
    int BS_total,
    int D) {
  const int T = num_tokens_p[0];
  const int BT = gridDim.x;
  const int S = (int)(((long long)BS_total * T) / BT);
  const int b = blockIdx.x / T;
  const int t = blockIdx.x - b * T;
  const int* __restrict__ row = seg + (size_t)b * S;

  int lo = 0, n = S;
  while (n > 0) {
    int half = n >> 1;
    int mid = lo + half;
    if (row[mid] < t) { lo = mid + 1; n -= half + 1; } else { n = half; }
  }
  int hi = lo; n = S - lo;
  while (n > 0) {
    int half = n >> 1;
    int mid = hi + half;
    if (row[mid] < t + 1) { hi = mid + 1; n -= half + 1; } else { n = half; }
  }
  const int cnt = hi - lo;

  const int d4 = threadIdx.x;
  const int rowstride4 = D >> 2;
  const float4* __restrict__ p =
      (const float4*)(hs + ((size_t)b * S + lo) * D) + d4;

  float4 acc = make_float4(0.f, 0.f, 0.f, 0.f);
  for (int s = 0; s < cnt; ++s) {
    float4 v = p[(size_t)s * rowstride4];
    acc.x += v.x; acc.y += v.y; acc.z += v.z; acc.w += v.w;
  }
  const float inv = (cnt > 0) ? (1.0f / (float)cnt) : 0.0f;
  float4 o = make_float4(acc.x * inv, acc.y * inv, acc.z * inv, acc.w * inv);
  ((float4*)(out + (size_t)blockIdx.x * D))[d4] = o;
}

extern "C" void kernel_launch(void* const* d_in, const int* in_sizes, int n_in,
                              void* d_out, int out_size, void* d_ws, size_t ws_size,
                              hipStream_t stream) {
  const float* hs = (const float*)d_in[0];
  const int* seg = (const int*)d_in[1];
  const int* num_tokens_p = (const int*)d_in[2];
  float* out = (float*)d_out;

  const int BS_total = in_sizes[1];            // B*S
  const int D = in_sizes[0] / in_sizes[1];     // 768
  const int BT = out_size / D;                 // B*T

  const size_t ws_needed = (size_t)8 * (size_t)BT;   // int2 per token

  if (ws_size >= ws_needed) {
    int2* pairs = (int2*)d_ws;

    const int threads1 = 256;
    const int grid1 = (BS_total + threads1 - 1) / threads1;
    hipLaunchKernelGGL(bounds_pairs_kernel, dim3(grid1), dim3(threads1), 0, stream,
                       seg, num_tokens_p, pairs, BS_total, BT);

    if (D == 768) {
      const int nChunks = (BS_total + CHUNK - 1) / CHUNK;
      const int nFix = (BT + 2) / 3;
      hipLaunchKernelGGL(seg_mean_chunk_d768, dim3(nChunks + nFix), dim3(192),
                         0, stream, hs, seg, pairs, num_tokens_p, out,
                         BS_total, BT, nChunks);
    } else {
      const int needBlocks = (BT + 3) / 4;
      const int grid2 = (needBlocks < 2048) ? needBlocks : 2048;
      hipLaunchKernelGGL(seg_mean_generic, dim3(grid2), dim3(256), 0,
                         stream, hs, pairs, out, BT, D / 4);
    }
  } else {
    hipLaunchKernelGGL(seg_mean_search_kernel, dim3(BT), dim3(D / 4), 0, stream,
                       hs, seg, num_tokens_p, out, BS_total, D);
  }
}

// Round 11
// 164.328 us; speedup vs baseline: 1.0394x; 1.0394x over previous
//
#include <hip/hip_runtime.h>

// Segment-mean of subtoken embeddings (sorted per-row segment ids) -> token means.
//
// FINAL: verbatim round-7 kernel — best harness-verified version (164.95 us,
// absmax 0.0). Structure: tiny one-block-per-token phase 2 with NONTEMPORAL
// loads+stores (confirmed mechanism: homogeneous HBM read stream instead of
// the ~2.1 TB/s mixed L3-hit/HBM-miss return path; -8 us measured).
// Falsified alternatives (rounds 1-9): block fusion, full-occupancy
// persistent grids, 4-deep software pipelines, write-allocate avoidance
// alone, 2-tokens-per-block amortization, chunk streaming, chunk+NT stack.
// Remaining gap to the ~27 us pure-stream floor (~44 us measured) is the
// irreducible cost of a data-dependent gather-mean at avg S/T=1.33
// rows/token; ~118 us of the timed total is harness fill outside kernel
// control.
//
// Phase 1 (bounds_pairs_kernel): pairs[b*T+t] = {global_lo, global_hi} row
// bounds per token; each field written exactly once (sorted ids => ownership).

typedef float f32x4_v __attribute__((ext_vector_type(4)));

__global__ void bounds_pairs_kernel(const int* __restrict__ seg,
                                    const int* __restrict__ num_tokens_p,
                                    int2* __restrict__ pairs,   // [B*T] global-row bounds
                                    int BS_total,               // B*S
                                    int BT) {                   // B*T
  const int T = num_tokens_p[0];
  const int B = BT / T;
  const int S = BS_total / B;
  const int idx = blockIdx.x * blockDim.x + threadIdx.x;
  if (idx >= BS_total) return;
  const int b = idx / S;
  const int s = idx - b * S;
  const int cur = seg[idx];
  const int prev = (s == 0) ? -1 : seg[idx - 1];
  int2* __restrict__ prow = pairs + (size_t)b * T;

  for (int t = prev + 1; t <= cur; ++t) {
    prow[t].x = idx;                 // lo(t): global row index
    if (t > 0) prow[t - 1].y = idx;  // hi(t-1) = lo(t)
  }
  if (s == S - 1) {
    const int end = b * S + S;
    for (int t = cur + 1; t <= T; ++t) {
      if (t < T) prow[t].x = end;
      prow[t - 1].y = end;
    }
  }
}

// One block per token, 192 threads (3 waves), lane owns one float4 column.
__global__ void __launch_bounds__(192) seg_mean_tok_d768(
    const float* __restrict__ hs,      // [B, S, 768]
    const int2*  __restrict__ pairs,   // [B*T]
    float*       __restrict__ out) {   // [B, T, 768]
  const int g = blockIdx.x;
  const int2 lh = pairs[g];            // one 8B broadcast load
  const int cnt = lh.y - lh.x;
  const int d4 = threadIdx.x;          // [0, 192)

  const f32x4_v* __restrict__ p =
      (const f32x4_v*)hs + (size_t)lh.x * 192 + d4;
  f32x4_v* __restrict__ q = (f32x4_v*)out + (size_t)g * 192 + d4;

  f32x4_v o;
  if (cnt == 1) {                      // ~35% of tokens: pure copy
    o = __builtin_nontemporal_load(p);
  } else if (cnt == 0) {               // ~26%: zeros, no loads at all
    o = (f32x4_v){0.f, 0.f, 0.f, 0.f};
  } else if (cnt == 2) {               // ~23%: two loads, one add
    f32x4_v a = __builtin_nontemporal_load(p);
    f32x4_v b = __builtin_nontemporal_load(p + 192);
    o = (a + b) * 0.5f;
  } else {                             // ~16%: sequential-order loop,
    f32x4_v acc = {0.f, 0.f, 0.f, 0.f};//        loads issued 2-deep
    int r = 0;
    for (; r + 1 < cnt; r += 2) {
      f32x4_v a = __builtin_nontemporal_load(p + (size_t)r * 192);
      f32x4_v b = __builtin_nontemporal_load(p + (size_t)(r + 1) * 192);
      acc = acc + a;                   // order preserved: a then b
      acc = acc + b;
    }
    if (r < cnt) {
      acc = acc + __builtin_nontemporal_load(p + (size_t)r * 192);
    }
    o = acc * (1.0f / (float)cnt);
  }

  // out is written once and never re-read: keep it out of L2/L3.
  __builtin_nontemporal_store(o, q);
}

// Generic-D fallback (D % 4 == 0): one wave per token, column-strided.
__global__ void __launch_bounds__(256) seg_mean_generic(
    const float* __restrict__ hs,
    const int2*  __restrict__ pairs,
    float*       __restrict__ out,
    int BT,
    int dv4) {
  const int wave = threadIdx.x >> 6;
  const int lane = threadIdx.x & 63;
  const int gstride = gridDim.x * 4;

  for (int g = blockIdx.x * 4 + wave; g < BT; g += gstride) {
    const int2 lh = pairs[g];
    const int cnt = lh.y - lh.x;
    const float inv = (cnt > 0) ? (1.0f / (float)cnt) : 0.0f;

    for (int c = lane; c < dv4; c += 64) {
      const float4* __restrict__ p = (const float4*)hs + (size_t)lh.x * dv4 + c;
      float4 acc = make_float4(0.f, 0.f, 0.f, 0.f);
      for (int r = 0; r < cnt; ++r) {
        float4 v = *p;
        acc.x += v.x; acc.y += v.y; acc.z += v.z; acc.w += v.w;
        p += dv4;
      }
      ((float4*)(out + (size_t)g * (dv4 * 4)))[c] =
          make_float4(acc.x * inv, acc.y * inv, acc.z * inv, acc.w * inv);
    }
  }
}

// Workspace-too-small fallback (correctness only).
__global__ void __launch_bounds__(192) seg_mean_search_kernel(
    const float* __restrict__ hs,
    const int* __restrict__ seg,
    const int* __restrict__ num_tokens_p,
    float* __restrict__ out,
    int BS_total,
    int D) {
  const int T = num_tokens_p[0];
  const int BT = gridDim.x;
  const int S = (int)(((long long)BS_total * T) / BT);
  const int b = blockIdx.x / T;
  const int t = blockIdx.x - b * T;
  const int* __restrict__ row = seg + (size_t)b * S;

  int lo = 0, n = S;
  while (n > 0) {
    int half = n >> 1;
    int mid = lo + half;
    if (row[mid] < t) { lo = mid + 1; n -= half + 1; } else { n = half; }
  }
  int hi = lo; n = S - lo;
  while (n > 0) {
    int half = n >> 1;
    int mid = hi + half;
    if (row[mid] < t + 1) { hi = mid + 1; n -= half + 1; } else { n = half; }
  }
  const int cnt = hi - lo;

  const int d4 = threadIdx.x;
  const int rowstride4 = D >> 2;
  const float4* __restrict__ p =
      (const float4*)(hs + ((size_t)b * S + lo) * D) + d4;

  float4 acc = make_float4(0.f, 0.f, 0.f, 0.f);
  for (int s = 0; s < cnt; ++s) {
    float4 v = p[(size_t)s * rowstride4];
    acc.x += v.x; acc.y += v.y; acc.z += v.z; acc.w += v.w;
  }
  const float inv = (cnt > 0) ? (1.0f / (float)cnt) : 0.0f;
  float4 o = make_float4(acc.x * inv, acc.y * inv, acc.z * inv, acc.w * inv);
  ((float4*)(out + (size_t)blockIdx.x * D))[d4] = o;
}

extern "C" void kernel_launch(void* const* d_in, const int* in_sizes, int n_in,
                              void* d_out, int out_size, void* d_ws, size_t ws_size,
                              hipStream_t stream) {
  const float* hs = (const float*)d_in[0];
  const int* seg = (const int*)d_in[1];
  const int* num_tokens_p = (const int*)d_in[2];
  float* out = (float*)d_out;

  const int BS_total = in_sizes[1];            // B*S
  const int D = in_sizes[0] / in_sizes[1];     // 768
  const int BT = out_size / D;                 // B*T

  const size_t ws_needed = (size_t)8 * (size_t)BT;   // int2 per token

  if (ws_size >= ws_needed) {
    int2* pairs = (int2*)d_ws;

    const int threads1 = 256;
    const int grid1 = (BS_total + threads1 - 1) / threads1;
    hipLaunchKernelGGL(bounds_pairs_kernel, dim3(grid1), dim3(threads1), 0, stream,
                       seg, num_tokens_p, pairs, BS_total, BT);

    if (D == 768) {
      hipLaunchKernelGGL(seg_mean_tok_d768, dim3(BT), dim3(192), 0, stream,
                         hs, pairs, out);
    } else {
      const int needBlocks = (BT + 3) / 4;
      const int grid2 = (needBlocks < 2048) ? needBlocks : 2048;
      hipLaunchKernelGGL(seg_mean_generic, dim3(grid2), dim3(256), 0,
                         stream, hs, pairs, out, BT, D / 4);
    }
  } else {
    hipLaunchKernelGGL(seg_mean_search_kernel, dim3(BT), dim3(D / 4), 0, stream,
                       hs, seg, num_tokens_p, out, BS_total, D);
  }
}